// Round 1
// baseline (763.756 us; speedup 1.0000x reference)
//
#include <hip/hip_runtime.h>

// Problem constants (fixed by setup_inputs: bs=8, N=M=4096, C=128)
#define BS 8
#define NN 4096
#define MM 4096
#define CC 128
#define TN 64
#define TM 64
#define TK 32

#define FINF_BITS 0x7F800000u

// ---------------------------------------------------------------------------
// init: set row/col running minima to +inf, zero the scalar output.
// (d_ws / d_out are poisoned 0xAA before every timed launch.)
// ---------------------------------------------------------------------------
__global__ void ch_init(unsigned* __restrict__ rowmin, unsigned* __restrict__ colmin,
                        float* __restrict__ out) {
    int i = blockIdx.x * blockDim.x + threadIdx.x;
    if (i < BS * NN) rowmin[i] = FINF_BITS;
    if (i < BS * MM) colmin[i] = FINF_BITS;
    if (i == 0) out[0] = 0.0f;
}

// ---------------------------------------------------------------------------
// norms: ||x_n||^2 and ||y_m||^2 per row. One thread per row, float4 loads.
// ---------------------------------------------------------------------------
__global__ void ch_norms(const float* __restrict__ x, const float* __restrict__ y,
                         float* __restrict__ xn, float* __restrict__ yn) {
    int i = blockIdx.x * blockDim.x + threadIdx.x;
    if (i >= BS * NN) return;
    const float4* px = (const float4*)(x + (size_t)i * CC);
    const float4* py = (const float4*)(y + (size_t)i * CC);
    float sx = 0.f, sy = 0.f;
#pragma unroll
    for (int j = 0; j < CC / 4; ++j) {
        float4 v = px[j];
        sx += v.x * v.x + v.y * v.y + v.z * v.z + v.w * v.w;
        float4 w = py[j];
        sy += w.x * w.x + w.y * w.y + w.z * w.z + w.w * w.w;
    }
    xn[i] = sx;
    yn[i] = sy;
}

// ---------------------------------------------------------------------------
// main tile kernel: 64x64 distance tile per block, 4x4 micro-tile per thread.
// xy inner products via register-blocked fp32 FMA over transposed LDS tiles.
// Epilogue: d = sqrt(max(x2+y2-2xy,0)); block-local min via LDS atomics,
// then one global atomicMin per row/col per block (uint trick, d >= 0).
// ---------------------------------------------------------------------------
__global__ __launch_bounds__(256) void ch_tile(
    const float* __restrict__ x, const float* __restrict__ y,
    const float* __restrict__ xn, const float* __restrict__ yn,
    unsigned* __restrict__ rowmin, unsigned* __restrict__ colmin) {

    __shared__ float xs[TK][TN + 1];   // transposed: xs[k][n]
    __shared__ float ys[TK][TM + 1];   // transposed: ys[k][m]
    __shared__ unsigned rmin[TN];
    __shared__ unsigned cmin[TM];

    const int b  = blockIdx.z;
    const int n0 = blockIdx.x * TN;
    const int m0 = blockIdx.y * TM;
    const int tid = threadIdx.x;

    const float* xb = x + ((size_t)b * NN + n0) * CC;
    const float* yb = y + ((size_t)b * MM + m0) * CC;

    if (tid < TN) rmin[tid] = FINF_BITS;
    if (tid < TM) cmin[tid] = FINF_BITS;

    float acc[4][4] = {};

    const int tn = (tid & 15) * 4;   // 4 consecutive rows
    const int tm = (tid >> 4) * 4;   // 4 consecutive cols

    for (int k0 = 0; k0 < CC; k0 += TK) {
        __syncthreads();
        // stage 64x32 sub-tiles of x and y, transposed into LDS.
        // TN*TK/4 = 512 float4s -> 2 per thread.
        for (int j = tid; j < TN * TK / 4; j += 256) {
            int n = j >> 3, kg = j & 7;
            float4 v = *(const float4*)(xb + (size_t)n * CC + k0 + kg * 4);
            xs[kg * 4 + 0][n] = v.x;
            xs[kg * 4 + 1][n] = v.y;
            xs[kg * 4 + 2][n] = v.z;
            xs[kg * 4 + 3][n] = v.w;
            float4 w = *(const float4*)(yb + (size_t)n * CC + k0 + kg * 4);
            ys[kg * 4 + 0][n] = w.x;
            ys[kg * 4 + 1][n] = w.y;
            ys[kg * 4 + 2][n] = w.z;
            ys[kg * 4 + 3][n] = w.w;
        }
        __syncthreads();
#pragma unroll
        for (int k = 0; k < TK; ++k) {
            float4 a  = *(const float4*)&xs[k][tn];
            float4 bv = *(const float4*)&ys[k][tm];
            float av[4] = {a.x, a.y, a.z, a.w};
            float bw[4] = {bv.x, bv.y, bv.z, bv.w};
#pragma unroll
            for (int i = 0; i < 4; ++i)
#pragma unroll
                for (int j = 0; j < 4; ++j)
                    acc[i][j] = fmaf(av[i], bw[j], acc[i][j]);
        }
    }

    // epilogue: distances + mins
    float xnr[4], ynr[4];
#pragma unroll
    for (int i = 0; i < 4; ++i) xnr[i] = xn[(size_t)b * NN + n0 + tn + i];
#pragma unroll
    for (int j = 0; j < 4; ++j) ynr[j] = yn[(size_t)b * MM + m0 + tm + j];

    float rm[4], cm[4];
#pragma unroll
    for (int i = 0; i < 4; ++i) rm[i] = __builtin_inff();
#pragma unroll
    for (int j = 0; j < 4; ++j) cm[j] = __builtin_inff();

#pragma unroll
    for (int i = 0; i < 4; ++i) {
#pragma unroll
        for (int j = 0; j < 4; ++j) {
            float d2 = xnr[i] + ynr[j] - 2.0f * acc[i][j];
            float d  = sqrtf(fmaxf(d2, 0.0f));
            rm[i] = fminf(rm[i], d);
            cm[j] = fminf(cm[j], d);
        }
    }

#pragma unroll
    for (int i = 0; i < 4; ++i) atomicMin(&rmin[tn + i], __float_as_uint(rm[i]));
#pragma unroll
    for (int j = 0; j < 4; ++j) atomicMin(&cmin[tm + j], __float_as_uint(cm[j]));
    __syncthreads();

    if (tid < TN)        atomicMin(&rowmin[(size_t)b * NN + n0 + tid], rmin[tid]);
    else if (tid < TN + TM) {
        int j = tid - TN;
        atomicMin(&colmin[(size_t)b * MM + m0 + j], cmin[j]);
    }
}

// ---------------------------------------------------------------------------
// finalize: total = (sum w1*rowmin + sum w2*colmin) / 2
// ---------------------------------------------------------------------------
__global__ void ch_finalize(const unsigned* __restrict__ rowmin,
                            const unsigned* __restrict__ colmin,
                            const float* __restrict__ w1,
                            const float* __restrict__ w2,
                            float* __restrict__ out) {
    int i = blockIdx.x * blockDim.x + threadIdx.x;
    int stride = gridDim.x * blockDim.x;
    float s = 0.f;
    for (int idx = i; idx < BS * NN; idx += stride)
        s += w1[idx] * __uint_as_float(rowmin[idx]) +
             w2[idx] * __uint_as_float(colmin[idx]);
    // wave64 reduce
#pragma unroll
    for (int off = 32; off > 0; off >>= 1) s += __shfl_down(s, off, 64);
    __shared__ float ls[4];
    int lane = threadIdx.x & 63, wv = threadIdx.x >> 6;
    if (lane == 0) ls[wv] = s;
    __syncthreads();
    if (threadIdx.x == 0) {
        float t = ls[0] + ls[1] + ls[2] + ls[3];
        atomicAdd(out, 0.5f * t);
    }
}

extern "C" void kernel_launch(void* const* d_in, const int* in_sizes, int n_in,
                              void* d_out, int out_size, void* d_ws, size_t ws_size,
                              hipStream_t stream) {
    const float* set1 = (const float*)d_in[0];
    const float* set2 = (const float*)d_in[1];
    const float* w1   = (const float*)d_in[2];
    const float* w2   = (const float*)d_in[3];
    float* out = (float*)d_out;

    // workspace layout
    unsigned* rowmin = (unsigned*)d_ws;            // BS*NN
    unsigned* colmin = rowmin + BS * NN;           // BS*MM
    float*    xn     = (float*)(colmin + BS * MM); // BS*NN
    float*    yn     = xn + BS * NN;               // BS*MM

    ch_init<<<(BS * NN + 255) / 256, 256, 0, stream>>>(rowmin, colmin, out);
    ch_norms<<<(BS * NN + 255) / 256, 256, 0, stream>>>(set1, set2, xn, yn);

    dim3 grid(NN / TN, MM / TM, BS);
    ch_tile<<<grid, 256, 0, stream>>>(set1, set2, xn, yn, rowmin, colmin);

    ch_finalize<<<32, 256, 0, stream>>>(rowmin, colmin, w1, w2, out);
}

// Round 2
// 218.390 us; speedup vs baseline: 3.4972x; 3.4972x over previous
//
#include <hip/hip_runtime.h>

// Problem constants (fixed by setup_inputs: bs=8, N=M=4096, C=128)
#define BS 8
#define NN 4096
#define MM 4096
#define CC 128
#define BM 128   // x-rows per block tile
#define BN 128   // y-rows per block tile
#define BK 32    // k per staging iteration

#define FINF_BITS 0x7F800000u

typedef __attribute__((ext_vector_type(8))) short bf16x8;
typedef __attribute__((ext_vector_type(4))) float f32x4;

// RNE fp32 -> bf16 (inputs are finite normals; NaN path not needed)
__device__ inline ushort f2bf(float f) {
    unsigned u = __float_as_uint(f);
    unsigned r = (u + 0x7FFFu + ((u >> 16) & 1u)) >> 16;
    return (ushort)r;
}

// ---------------------------------------------------------------------------
// init: minima to +inf, zero the output scalar (ws/out are poisoned 0xAA).
// ---------------------------------------------------------------------------
__global__ void ch_init(unsigned* __restrict__ rowmin, unsigned* __restrict__ colmin,
                        float* __restrict__ out) {
    int i = blockIdx.x * blockDim.x + threadIdx.x;
    if (i < BS * NN) rowmin[i] = FINF_BITS;
    if (i < BS * MM) colmin[i] = FINF_BITS;
    if (i == 0) out[0] = 0.0f;
}

// ---------------------------------------------------------------------------
// convert: fp32 -> bf16 copies of both sets (memory-bound, float4 in/ushort4 out)
// ---------------------------------------------------------------------------
__global__ void ch_convert(const float* __restrict__ x, const float* __restrict__ y,
                           ushort* __restrict__ x16, ushort* __restrict__ y16) {
    size_t i = ((size_t)blockIdx.x * blockDim.x + threadIdx.x) * 4;
    float4 v = *(const float4*)(x + i);
    ushort4 o;
    o.x = f2bf(v.x); o.y = f2bf(v.y); o.z = f2bf(v.z); o.w = f2bf(v.w);
    *(ushort4*)(x16 + i) = o;
    float4 w = *(const float4*)(y + i);
    ushort4 p;
    p.x = f2bf(w.x); p.y = f2bf(w.y); p.z = f2bf(w.z); p.w = f2bf(w.w);
    *(ushort4*)(y16 + i) = p;
}

// ---------------------------------------------------------------------------
// norms: exact fp32 ||row||^2 for both sets
// ---------------------------------------------------------------------------
__global__ void ch_norms(const float* __restrict__ x, const float* __restrict__ y,
                         float* __restrict__ xn, float* __restrict__ yn) {
    int i = blockIdx.x * blockDim.x + threadIdx.x;
    if (i >= BS * NN) return;
    const float4* px = (const float4*)(x + (size_t)i * CC);
    const float4* py = (const float4*)(y + (size_t)i * CC);
    float sx = 0.f, sy = 0.f;
#pragma unroll
    for (int j = 0; j < CC / 4; ++j) {
        float4 v = px[j];
        sx += v.x * v.x + v.y * v.y + v.z * v.z + v.w * v.w;
        float4 w = py[j];
        sy += w.x * w.x + w.y * w.y + w.z * w.z + w.w * w.w;
    }
    xn[i] = sx;
    yn[i] = sy;
}

// ---------------------------------------------------------------------------
// main tile kernel (m97 structure): 128x128 distance tile per block,
// bf16 16x16x32 MFMA for xy, global_load_lds width-16 staging, BK=32.
// 4 waves, each computes a 64x64 quadrant as 4x4 MFMAs.
// Epilogue: d=sqrt(max(xn+yn-2xy,0)); shuffle-reduced row/col mins ->
// LDS atomicMin -> one global atomicMin per row/col per block.
// ---------------------------------------------------------------------------
__global__ __launch_bounds__(256) void ch_tile(
    const ushort* __restrict__ X, const ushort* __restrict__ Y,
    const float* __restrict__ xn, const float* __restrict__ yn,
    unsigned* __restrict__ rowmin, unsigned* __restrict__ colmin) {

    __shared__ ushort xs[BM * BK];      // [row][k], 64B rows, packed (no pad: global_load_lds)
    __shared__ ushort ys[BN * BK];
    __shared__ unsigned rowtile[BM];
    __shared__ unsigned coltile[BN];

    const int b  = blockIdx.z;
    const int n0 = blockIdx.x * BM;     // x-row tile base
    const int m0 = blockIdx.y * BN;     // y-row tile base
    const int tid  = threadIdx.x;
    const int wave = tid >> 6;
    const int lane = tid & 63;
    const int lc   = lane & 15;         // MFMA: A/B row index, C col index
    const int quad = lane >> 4;         // MFMA: k-group, C row group
    const int wm = wave >> 1;           // row half (0/1)
    const int wn = wave & 1;            // col half (0/1)

    if (tid < BM) rowtile[tid] = FINF_BITS;
    if (tid < BN) coltile[tid] = FINF_BITS;

    const ushort* Xb = X + ((size_t)b * NN + n0) * CC;
    const ushort* Yb = Y + ((size_t)b * MM + m0) * CC;

    f32x4 acc[4][4] = {};

    for (int k0 = 0; k0 < CC; k0 += BK) {
        if (k0) __syncthreads();        // LDS reads of previous tile done
#pragma unroll
        for (int s = 0; s < 2; ++s) {
            // flat 16B chunk id: covers 128 rows x 64B; row = flat>>2, chunk = flat&3
            int flat = s * 256 + tid;
            int row = flat >> 2, ch = flat & 3;
            const ushort* gx = Xb + (size_t)row * CC + k0 + ch * 8;
            const ushort* gy = Yb + (size_t)row * CC + k0 + ch * 8;
            // wave-uniform LDS base; HW adds lane*16
            ushort* lx = xs + (size_t)(s * 256 + wave * 64) * 8;
            ushort* ly = ys + (size_t)(s * 256 + wave * 64) * 8;
            __builtin_amdgcn_global_load_lds(
                (const __attribute__((address_space(1))) void*)gx,
                (__attribute__((address_space(3))) void*)lx, 16, 0, 0);
            __builtin_amdgcn_global_load_lds(
                (const __attribute__((address_space(1))) void*)gy,
                (__attribute__((address_space(3))) void*)ly, 16, 0, 0);
        }
        __syncthreads();                // drains vmcnt(0) then barrier

        bf16x8 af[4], bf[4];
#pragma unroll
        for (int i = 0; i < 4; ++i)
            af[i] = *(const bf16x8*)(xs + (wm * 64 + i * 16 + lc) * BK + quad * 8);
#pragma unroll
        for (int j = 0; j < 4; ++j)
            bf[j] = *(const bf16x8*)(ys + (wn * 64 + j * 16 + lc) * BK + quad * 8);
#pragma unroll
        for (int i = 0; i < 4; ++i)
#pragma unroll
            for (int j = 0; j < 4; ++j)
                acc[i][j] = __builtin_amdgcn_mfma_f32_16x16x32_bf16(
                    af[i], bf[j], acc[i][j], 0, 0, 0);
    }

    // ---- epilogue ----
    // C/D layout: col = lc (y index), row = quad*4 + reg (x index)
    float xnr[4][4], ynr[4];
#pragma unroll
    for (int i = 0; i < 4; ++i)
#pragma unroll
        for (int r = 0; r < 4; ++r)
            xnr[i][r] = xn[(size_t)b * NN + n0 + wm * 64 + i * 16 + quad * 4 + r];
#pragma unroll
    for (int j = 0; j < 4; ++j)
        ynr[j] = yn[(size_t)b * MM + m0 + wn * 64 + j * 16 + lc];

    float rm[4][4], cm[4];
#pragma unroll
    for (int i = 0; i < 4; ++i)
#pragma unroll
        for (int r = 0; r < 4; ++r) rm[i][r] = __builtin_inff();
#pragma unroll
    for (int j = 0; j < 4; ++j) cm[j] = __builtin_inff();

#pragma unroll
    for (int i = 0; i < 4; ++i) {
#pragma unroll
        for (int j = 0; j < 4; ++j) {
            f32x4 a = acc[i][j];
#pragma unroll
            for (int r = 0; r < 4; ++r) {
                float d2 = xnr[i][r] + ynr[j] - 2.0f * a[r];
                float d  = sqrtf(fmaxf(d2, 0.0f));
                rm[i][r] = fminf(rm[i][r], d);
                cm[j]    = fminf(cm[j], d);
            }
        }
    }

    // row mins: reduce across the 16 lanes (lc) sharing the same rows
#pragma unroll
    for (int mask = 1; mask <= 8; mask <<= 1)
#pragma unroll
        for (int i = 0; i < 4; ++i)
#pragma unroll
            for (int r = 0; r < 4; ++r)
                rm[i][r] = fminf(rm[i][r], __shfl_xor(rm[i][r], mask, 64));
    if (lc == 0) {
#pragma unroll
        for (int i = 0; i < 4; ++i)
#pragma unroll
            for (int r = 0; r < 4; ++r)
                atomicMin(&rowtile[wm * 64 + i * 16 + quad * 4 + r],
                          __float_as_uint(rm[i][r]));
    }

    // col mins: reduce across the 4 quads sharing the same cols
#pragma unroll
    for (int mask = 16; mask <= 32; mask <<= 1)
#pragma unroll
        for (int j = 0; j < 4; ++j)
            cm[j] = fminf(cm[j], __shfl_xor(cm[j], mask, 64));
    if (quad == 0) {
#pragma unroll
        for (int j = 0; j < 4; ++j)
            atomicMin(&coltile[wn * 64 + j * 16 + lc], __float_as_uint(cm[j]));
    }

    __syncthreads();
    if (tid < BM)
        atomicMin(&rowmin[(size_t)b * NN + n0 + tid], rowtile[tid]);
    else
        atomicMin(&colmin[(size_t)b * MM + m0 + (tid - BM)], coltile[tid - BM]);
}

// ---------------------------------------------------------------------------
// finalize: total = (sum w1*rowmin + sum w2*colmin) / 2
// ---------------------------------------------------------------------------
__global__ void ch_finalize(const unsigned* __restrict__ rowmin,
                            const unsigned* __restrict__ colmin,
                            const float* __restrict__ w1,
                            const float* __restrict__ w2,
                            float* __restrict__ out) {
    int i = blockIdx.x * blockDim.x + threadIdx.x;
    int stride = gridDim.x * blockDim.x;
    float s = 0.f;
    for (int idx = i; idx < BS * NN; idx += stride)
        s += w1[idx] * __uint_as_float(rowmin[idx]) +
             w2[idx] * __uint_as_float(colmin[idx]);
#pragma unroll
    for (int off = 32; off > 0; off >>= 1) s += __shfl_down(s, off, 64);
    __shared__ float ls[4];
    int lane = threadIdx.x & 63, wv = threadIdx.x >> 6;
    if (lane == 0) ls[wv] = s;
    __syncthreads();
    if (threadIdx.x == 0) {
        float t = ls[0] + ls[1] + ls[2] + ls[3];
        atomicAdd(out, 0.5f * t);
    }
}

extern "C" void kernel_launch(void* const* d_in, const int* in_sizes, int n_in,
                              void* d_out, int out_size, void* d_ws, size_t ws_size,
                              hipStream_t stream) {
    const float* set1 = (const float*)d_in[0];
    const float* set2 = (const float*)d_in[1];
    const float* w1   = (const float*)d_in[2];
    const float* w2   = (const float*)d_in[3];
    float* out = (float*)d_out;

    // workspace layout (~16.5 MiB total)
    ushort*   x16    = (ushort*)d_ws;                      // BS*NN*CC bf16
    ushort*   y16    = x16 + (size_t)BS * NN * CC;         // BS*MM*CC bf16
    unsigned* rowmin = (unsigned*)(y16 + (size_t)BS * MM * CC); // BS*NN
    unsigned* colmin = rowmin + BS * NN;                   // BS*MM
    float*    xn     = (float*)(colmin + BS * MM);         // BS*NN
    float*    yn     = xn + BS * NN;                       // BS*MM

    ch_init<<<(BS * NN + 255) / 256, 256, 0, stream>>>(rowmin, colmin, out);
    ch_convert<<<(BS * NN * CC / 4 + 255) / 256, 256, 0, stream>>>(set1, set2, x16, y16);
    ch_norms<<<(BS * NN + 255) / 256, 256, 0, stream>>>(set1, set2, xn, yn);

    dim3 grid(NN / BM, MM / BN, BS);
    ch_tile<<<grid, 256, 0, stream>>>(x16, y16, xn, yn, rowmin, colmin);

    ch_finalize<<<32, 256, 0, stream>>>(rowmin, colmin, w1, w2, out);
}

// Round 3
// 163.141 us; speedup vs baseline: 4.6816x; 1.3387x over previous
//
#include <hip/hip_runtime.h>

// Problem constants (fixed by setup_inputs: bs=8, N=M=4096, C=128)
#define BS 8
#define NN 4096
#define MM 4096
#define CC 128
#define BM 128   // x-rows per block tile
#define BN 128   // y-rows per block tile
#define BK 64    // k per staging iteration (2 iters over C=128)

#define FINF_BITS 0x7F800000u

typedef __attribute__((ext_vector_type(8))) short bf16x8;
typedef __attribute__((ext_vector_type(4))) float f32x4;

// RNE fp32 -> bf16 (inputs are finite normals; NaN path not needed)
__device__ inline ushort f2bf(float f) {
    unsigned u = __float_as_uint(f);
    unsigned r = (u + 0x7FFFu + ((u >> 16) & 1u)) >> 16;
    return (ushort)r;
}

// ---------------------------------------------------------------------------
// prep (fused init + convert + norms):
//  - fp32 -> bf16 copies of both sets (one read pass, float4/ushort4)
//  - exact fp32 row norms via 32-lane segmented shuffle reduce
//  - rowmin/colmin = +inf, out = 0  (ws/out are poisoned 0xAA each call)
// grid: BS*NN*CC/4 threads; each thread owns one float4 of x and one of y.
// ---------------------------------------------------------------------------
__global__ void ch_prep(const float* __restrict__ x, const float* __restrict__ y,
                        ushort* __restrict__ x16, ushort* __restrict__ y16,
                        float* __restrict__ xn, float* __restrict__ yn,
                        unsigned* __restrict__ rowmin, unsigned* __restrict__ colmin,
                        float* __restrict__ out) {
    int gid = blockIdx.x * blockDim.x + threadIdx.x;
    size_t i = (size_t)gid * 4;

    float4 v = *(const float4*)(x + i);
    ushort4 o;
    o.x = f2bf(v.x); o.y = f2bf(v.y); o.z = f2bf(v.z); o.w = f2bf(v.w);
    *(ushort4*)(x16 + i) = o;
    float sx = v.x * v.x + v.y * v.y + v.z * v.z + v.w * v.w;

    float4 w = *(const float4*)(y + i);
    ushort4 p;
    p.x = f2bf(w.x); p.y = f2bf(w.y); p.z = f2bf(w.z); p.w = f2bf(w.w);
    *(ushort4*)(y16 + i) = p;
    float sy = w.x * w.x + w.y * w.y + w.z * w.z + w.w * w.w;

    // 32 consecutive lanes cover one row (128 floats / 4) — xor masks <=16
    // stay inside each 32-lane segment of the wave64.
#pragma unroll
    for (int mask = 1; mask <= 16; mask <<= 1) {
        sx += __shfl_xor(sx, mask, 64);
        sy += __shfl_xor(sy, mask, 64);
    }
    if ((threadIdx.x & 31) == 0) {
        int row = gid >> 5;
        xn[row] = sx;
        yn[row] = sy;
    }

    if (gid < BS * NN) {
        rowmin[gid] = FINF_BITS;
        colmin[gid] = FINF_BITS;
    }
    if (gid == 0) out[0] = 0.0f;
}

// ---------------------------------------------------------------------------
// main tile kernel: 128x128 distance tile per block, bf16 16x16x32 MFMA,
// global_load_lds width-16 staging with XOR chunk swizzle (kills the
// row-stride bank aliasing: reads land 2-way/bank = free), BK=64 -> only
// 4 barriers per block. Epilogue reduces CLAMPED d^2 (sqrt deferred to
// finalize; min is monotone under sqrt) via shuffles -> LDS atomicMin ->
// one global atomicMin per row/col per block.
// ---------------------------------------------------------------------------
__global__ __launch_bounds__(256) void ch_tile(
    const ushort* __restrict__ X, const ushort* __restrict__ Y,
    const float* __restrict__ xn, const float* __restrict__ yn,
    unsigned* __restrict__ rowmin, unsigned* __restrict__ colmin) {

    __shared__ ushort xs[BM * BK];      // [row][slot], slot = chunk ^ (row&7)
    __shared__ ushort ys[BN * BK];
    __shared__ unsigned rowtile[BM];
    __shared__ unsigned coltile[BN];

    const int b  = blockIdx.z;
    const int n0 = blockIdx.x * BM;
    const int m0 = blockIdx.y * BN;
    const int tid  = threadIdx.x;
    const int wave = tid >> 6;
    const int lane = tid & 63;
    const int lc   = lane & 15;         // MFMA: A/B row index, C col index
    const int quad = lane >> 4;         // MFMA: k-group, C row group
    const int wm = wave >> 1;           // row half (0/1)
    const int wn = wave & 1;            // col half (0/1)

    if (tid < BM) rowtile[tid] = FINF_BITS;
    if (tid < BN) coltile[tid] = FINF_BITS;

    const ushort* Xb = X + ((size_t)b * NN + n0) * CC;
    const ushort* Yb = Y + ((size_t)b * MM + m0) * CC;

    // staging invariants: flat chunk f = s*256 + tid; row = f>>3, slot = tid&7.
    // lane loads SWIZZLED global chunk ch' = slot ^ (row&7) so that flat
    // lane-order LDS writes produce the swizzled layout.
    const int srow = tid >> 3;                    // row offset within 32-row group
    const int sch  = (tid & 7) ^ (srow & 7);      // swizzled global chunk (16B units)

    f32x4 acc[4][4] = {};

    for (int k0 = 0; k0 < CC; k0 += BK) {
        if (k0) __syncthreads();        // prev tile's LDS reads done
#pragma unroll
        for (int s = 0; s < 4; ++s) {
            int row = s * 32 + srow;
            const ushort* gx = Xb + (size_t)row * CC + k0 + sch * 8;
            const ushort* gy = Yb + (size_t)row * CC + k0 + sch * 8;
            ushort* lx = xs + s * 2048 + wave * 512;   // wave-uniform base
            ushort* ly = ys + s * 2048 + wave * 512;
            __builtin_amdgcn_global_load_lds(
                (const __attribute__((address_space(1))) void*)gx,
                (__attribute__((address_space(3))) void*)lx, 16, 0, 0);
            __builtin_amdgcn_global_load_lds(
                (const __attribute__((address_space(1))) void*)gy,
                (__attribute__((address_space(3))) void*)ly, 16, 0, 0);
        }
        __syncthreads();                // drains vmcnt(0), then barrier

#pragma unroll
        for (int t = 0; t < 2; ++t) {
            const int sw = ((t * 4 + quad) ^ (lc & 7)) * 8;  // swizzled k-offset
            bf16x8 af[4], bf[4];
#pragma unroll
            for (int i = 0; i < 4; ++i)
                af[i] = *(const bf16x8*)(xs + (wm * 64 + i * 16 + lc) * BK + sw);
#pragma unroll
            for (int j = 0; j < 4; ++j)
                bf[j] = *(const bf16x8*)(ys + (wn * 64 + j * 16 + lc) * BK + sw);
#pragma unroll
            for (int i = 0; i < 4; ++i)
#pragma unroll
                for (int j = 0; j < 4; ++j)
                    acc[i][j] = __builtin_amdgcn_mfma_f32_16x16x32_bf16(
                        af[i], bf[j], acc[i][j], 0, 0, 0);
        }
    }

    // ---- epilogue: min over clamped d^2 (sqrt deferred to finalize) ----
    // C/D layout: col = lc (y index), row = quad*4 + reg (x index)
    float xnr[4][4], ynr[4];
#pragma unroll
    for (int i = 0; i < 4; ++i)
#pragma unroll
        for (int r = 0; r < 4; ++r)
            xnr[i][r] = xn[(size_t)b * NN + n0 + wm * 64 + i * 16 + quad * 4 + r];
#pragma unroll
    for (int j = 0; j < 4; ++j)
        ynr[j] = yn[(size_t)b * MM + m0 + wn * 64 + j * 16 + lc];

    float rm[4][4], cm[4];
#pragma unroll
    for (int i = 0; i < 4; ++i)
#pragma unroll
        for (int r = 0; r < 4; ++r) rm[i][r] = __builtin_inff();
#pragma unroll
    for (int j = 0; j < 4; ++j) cm[j] = __builtin_inff();

#pragma unroll
    for (int i = 0; i < 4; ++i) {
#pragma unroll
        for (int j = 0; j < 4; ++j) {
            f32x4 a = acc[i][j];
#pragma unroll
            for (int r = 0; r < 4; ++r) {
                float d2 = fmaxf(xnr[i][r] + fmaf(-2.0f, a[r], ynr[j]), 0.0f);
                rm[i][r] = fminf(rm[i][r], d2);
                cm[j]    = fminf(cm[j], d2);
            }
        }
    }

    // row mins: reduce across the 16 lanes (lc) sharing the same rows
#pragma unroll
    for (int mask = 1; mask <= 8; mask <<= 1)
#pragma unroll
        for (int i = 0; i < 4; ++i)
#pragma unroll
            for (int r = 0; r < 4; ++r)
                rm[i][r] = fminf(rm[i][r], __shfl_xor(rm[i][r], mask, 64));
    if (lc == 0) {
#pragma unroll
        for (int i = 0; i < 4; ++i)
#pragma unroll
            for (int r = 0; r < 4; ++r)
                atomicMin(&rowtile[wm * 64 + i * 16 + quad * 4 + r],
                          __float_as_uint(rm[i][r]));
    }

    // col mins: reduce across the 4 quads sharing the same cols
#pragma unroll
    for (int mask = 16; mask <= 32; mask <<= 1)
#pragma unroll
        for (int j = 0; j < 4; ++j)
            cm[j] = fminf(cm[j], __shfl_xor(cm[j], mask, 64));
    if (quad == 0) {
#pragma unroll
        for (int j = 0; j < 4; ++j)
            atomicMin(&coltile[wn * 64 + j * 16 + lc], __float_as_uint(cm[j]));
    }

    __syncthreads();
    if (tid < BM)
        atomicMin(&rowmin[(size_t)b * NN + n0 + tid], rowtile[tid]);
    else
        atomicMin(&colmin[(size_t)b * MM + m0 + (tid - BM)], coltile[tid - BM]);
}

// ---------------------------------------------------------------------------
// finalize: total = (sum w1*sqrt(rowmin_d2) + sum w2*sqrt(colmin_d2)) / 2
// ---------------------------------------------------------------------------
__global__ void ch_finalize(const unsigned* __restrict__ rowmin,
                            const unsigned* __restrict__ colmin,
                            const float* __restrict__ w1,
                            const float* __restrict__ w2,
                            float* __restrict__ out) {
    int i = blockIdx.x * blockDim.x + threadIdx.x;
    int stride = gridDim.x * blockDim.x;
    float s = 0.f;
    for (int idx = i; idx < BS * NN; idx += stride)
        s += w1[idx] * sqrtf(__uint_as_float(rowmin[idx])) +
             w2[idx] * sqrtf(__uint_as_float(colmin[idx]));
#pragma unroll
    for (int off = 32; off > 0; off >>= 1) s += __shfl_down(s, off, 64);
    __shared__ float ls[4];
    int lane = threadIdx.x & 63, wv = threadIdx.x >> 6;
    if (lane == 0) ls[wv] = s;
    __syncthreads();
    if (threadIdx.x == 0) {
        float t = ls[0] + ls[1] + ls[2] + ls[3];
        atomicAdd(out, 0.5f * t);
    }
}

extern "C" void kernel_launch(void* const* d_in, const int* in_sizes, int n_in,
                              void* d_out, int out_size, void* d_ws, size_t ws_size,
                              hipStream_t stream) {
    const float* set1 = (const float*)d_in[0];
    const float* set2 = (const float*)d_in[1];
    const float* w1   = (const float*)d_in[2];
    const float* w2   = (const float*)d_in[3];
    float* out = (float*)d_out;

    // workspace layout (~16.5 MiB total)
    ushort*   x16    = (ushort*)d_ws;                      // BS*NN*CC bf16
    ushort*   y16    = x16 + (size_t)BS * NN * CC;         // BS*MM*CC bf16
    unsigned* rowmin = (unsigned*)(y16 + (size_t)BS * MM * CC); // BS*NN (d^2 bits)
    unsigned* colmin = rowmin + BS * NN;                   // BS*MM (d^2 bits)
    float*    xn     = (float*)(colmin + BS * MM);         // BS*NN
    float*    yn     = xn + BS * NN;                       // BS*MM

    ch_prep<<<BS * NN * CC / 4 / 256, 256, 0, stream>>>(
        set1, set2, x16, y16, xn, yn, rowmin, colmin, out);

    dim3 grid(NN / BM, MM / BN, BS);
    ch_tile<<<grid, 256, 0, stream>>>(x16, y16, xn, yn, rowmin, colmin);

    ch_finalize<<<32, 256, 0, stream>>>(rowmin, colmin, w1, w2, out);
}